// Round 3
// baseline (706.591 us; speedup 1.0000x reference)
//
#include <hip/hip_runtime.h>
#include <stdint.h>

#define TOPK 100
#define GCAP 2048
#define SCORE_TPB 512
#define TILE_ROWS 128
#define TILES_PER_BLOCK 1
#define ROWS_PER_BLOCK (TILE_ROWS * TILES_PER_BLOCK)

__device__ __forceinline__ unsigned int fsort(float f) {
  unsigned int u = __float_as_uint(f);
  return (u & 0x80000000u) ? ~u : (u | 0x80000000u);
}
__device__ __forceinline__ float funsort(unsigned int k) {
  unsigned int u = (k & 0x80000000u) ? (k ^ 0x80000000u) : ~k;
  return __uint_as_float(u);
}

// ---------------- Kernel 1: per-user sample threshold ----------------
__global__ void k_sample(const float* __restrict__ user,
                         const float* __restrict__ corpus,
                         float* __restrict__ thr,
                         int M, int rank) {
  __shared__ float s_scores[16384];
  __shared__ float s_user[64];
  __shared__ unsigned int s_hist[256];
  __shared__ float s_wred[8];
  __shared__ float s_bmax, s_bmin;

  const int u = blockIdx.x;
  const int t = threadIdx.x;
  if (t < 64) s_user[t] = user[u * 64 + t];
  __syncthreads();

  float uv[64];
#pragma unroll
  for (int i = 0; i < 64; ++i) uv[i] = s_user[i];

  float lmax = -3.0e38f, lmin = 3.0e38f;
  for (int r = t; r < M; r += 256) {
    const float4* row = (const float4*)(corpus + (size_t)r * 64);
    float acc = 0.f;
#pragma unroll
    for (int i = 0; i < 16; ++i) {
      float4 c = row[i];
      acc = fmaf(uv[4*i+0], c.x, acc);
      acc = fmaf(uv[4*i+1], c.y, acc);
      acc = fmaf(uv[4*i+2], c.z, acc);
      acc = fmaf(uv[4*i+3], c.w, acc);
    }
    s_scores[r] = acc;
    lmax = fmaxf(lmax, acc);
    lmin = fminf(lmin, acc);
  }
#pragma unroll
  for (int o = 32; o > 0; o >>= 1) {
    lmax = fmaxf(lmax, __shfl_down(lmax, o));
    lmin = fminf(lmin, __shfl_down(lmin, o));
  }
  if ((t & 63) == 0) { s_wred[t >> 6] = lmax; s_wred[4 + (t >> 6)] = lmin; }
  s_hist[t] = 0u;
  __syncthreads();
  if (t == 0) {
    float bm = s_wred[0], bn = s_wred[4];
    for (int w = 1; w < 4; ++w) { bm = fmaxf(bm, s_wred[w]); bn = fminf(bn, s_wred[4 + w]); }
    s_bmax = bm; s_bmin = bn;
  }
  __syncthreads();
  const float bmax = s_bmax, bmin = s_bmin;
  const float width = (bmax - bmin) / 256.0f;
  const float inv = (width > 0.f) ? 1.0f / width : 0.f;
  for (int r = t; r < M; r += 256) {
    int b = (int)((s_scores[r] - bmin) * inv);
    b = min(max(b, 0), 255);
    atomicAdd(&s_hist[b], 1u);
  }
  __syncthreads();
  if (t == 0) {
    unsigned int cum = 0;
    int b = 255;
    for (; b >= 0; --b) { cum += s_hist[b]; if (cum >= (unsigned int)rank) break; }
    if (b < 0) b = 0;
    thr[u] = bmin + width * (float)b;   // lower edge: conservative
  }
}

// ---------------- Kernel 2: blocked scoring + threshold filter ----------------
// 512 threads; block tile = 256 users x 128 rows; thread tile = 8 users x 8 rows.
// Both panels transposed (d-major) in LDS, D split into two 32-dim halves so
// static LDS = 50 KB -> 2 blocks/CU. Per d-step: 4 ds_read_b128 -> 64 FMA
// (16 FMA per b128 = LDS pipe balanced against VALU).
__global__ __launch_bounds__(SCORE_TPB) void k_score(
    const float* __restrict__ user,
    const float* __restrict__ corpus,
    const float* __restrict__ thr,
    unsigned int* __restrict__ cnt,
    unsigned long long* __restrict__ cand,
    int N, int CAP) {
  __shared__ __align__(16) float U[32][264];    // 33792 B, stride 1056 B (16B-aligned)
  __shared__ __align__(16) float Cc[32][136];   // 17408 B, stride 544 B (16B-aligned)

  const int t  = threadIdx.x;
  const int ut = t & 31;        // user-tile: users ut*8 .. ut*8+7
  const int rt = t >> 5;        // row-tile:  rows  rt*8 .. rt*8+7 (0..15)
  const long long base = (long long)blockIdx.x * ROWS_PER_BLOCK;

  float thv[8];
#pragma unroll
  for (int i = 0; i < 8; ++i) thv[i] = thr[ut * 8 + i];

  // staging assignments (wave-uniform group ids -> conflict-free LDS writes)
  const int su  = t & 255;      // user staged by this thread
  const int sdg = t >> 8;       // 0/1: which 16-dim group of the half
  const int sr  = t & 127;      // row staged by this thread
  const int scg = t >> 7;       // 0..3: which 8-dim group of the half

  for (int tile = 0; tile < TILES_PER_BLOCK; ++tile) {
    float acc[8][8];
#pragma unroll
    for (int i = 0; i < 8; ++i)
#pragma unroll
      for (int j = 0; j < 8; ++j) acc[i][j] = 0.f;

    const long long trow0 = base + (long long)tile * TILE_ROWS;

    for (int kh = 0; kh < 2; ++kh) {
      __syncthreads();   // previous compute done before overwriting LDS
      // ---- stage U half: thread loads 16 dims of user su ----
      {
        const float* up = user + su * 64 + kh * 32 + sdg * 16;
        float4 a = *(const float4*)(up + 0);
        float4 b = *(const float4*)(up + 4);
        float4 c = *(const float4*)(up + 8);
        float4 d = *(const float4*)(up + 12);
        float tmp[16] = {a.x,a.y,a.z,a.w, b.x,b.y,b.z,b.w,
                         c.x,c.y,c.z,c.w, d.x,d.y,d.z,d.w};
#pragma unroll
        for (int k = 0; k < 16; ++k) U[sdg * 16 + k][su] = tmp[k];
      }
      // ---- stage C half: thread loads 8 dims of row trow0+sr ----
      {
        const long long gr = trow0 + sr;
        float tmp[8] = {0.f,0.f,0.f,0.f,0.f,0.f,0.f,0.f};
        if (gr < (long long)N) {
          const float4* cp = (const float4*)(corpus + gr * 64 + kh * 32 + scg * 8);
          float4 a = cp[0], b = cp[1];
          tmp[0]=a.x; tmp[1]=a.y; tmp[2]=a.z; tmp[3]=a.w;
          tmp[4]=b.x; tmp[5]=b.y; tmp[6]=b.z; tmp[7]=b.w;
        }
#pragma unroll
        for (int k = 0; k < 8; ++k) Cc[scg * 8 + k][sr] = tmp[k];
      }
      __syncthreads();
      // ---- compute 32 d-steps ----
#pragma unroll 8
      for (int dd = 0; dd < 32; ++dd) {
        float4 ua = *(const float4*)&U[dd][ut * 8];
        float4 ub = *(const float4*)&U[dd][ut * 8 + 4];
        float4 ca = *(const float4*)&Cc[dd][rt * 8];
        float4 cb = *(const float4*)&Cc[dd][rt * 8 + 4];
        float us[8] = {ua.x,ua.y,ua.z,ua.w, ub.x,ub.y,ub.z,ub.w};
        float rs[8] = {ca.x,ca.y,ca.z,ca.w, cb.x,cb.y,cb.z,cb.w};
#pragma unroll
        for (int i = 0; i < 8; ++i)
#pragma unroll
          for (int j = 0; j < 8; ++j)
            acc[i][j] = fmaf(us[i], rs[j], acc[i][j]);
      }
    }
    // ---- filter ----
#pragma unroll
    for (int j = 0; j < 8; ++j) {
      const long long grow = trow0 + rt * 8 + j;
      if (grow < (long long)N) {
#pragma unroll
        for (int i = 0; i < 8; ++i) {
          if (acc[i][j] >= thv[i]) {
            const int u = ut * 8 + i;
            unsigned int pos = atomicAdd(&cnt[u], 1u);
            if (pos < (unsigned int)CAP) {
              unsigned long long key = ((unsigned long long)fsort(acc[i][j]) << 32)
                                     | (unsigned long long)(~(unsigned int)grow);
              cand[(size_t)u * (size_t)CAP + pos] = key;
            }
          }
        }
      }
    }
  }
}

// ---------------- Kernel 3: exact top-100 per user ----------------
__global__ void k_select(const unsigned long long* __restrict__ cand,
                         const unsigned int* __restrict__ cnt,
                         const float* __restrict__ thr,
                         float* __restrict__ out,
                         int B, int CAP) {
  __shared__ unsigned long long keys[GCAP];
  __shared__ unsigned int hist[1024];
  __shared__ unsigned int s_kmax, s_gcnt;
  __shared__ int s_bstar;

  const int u = blockIdx.x;
  const int t = threadIdx.x;
  const int n = min((int)cnt[u], CAP);
  const unsigned long long* cu = cand + (size_t)u * (size_t)CAP;
  const unsigned int kmin = fsort(thr[u]);

  if (t == 0) { s_kmax = 0u; s_gcnt = 0u; }
  for (int i = t; i < 1024; i += 256) hist[i] = 0u;
  __syncthreads();

  unsigned int lmax = 0u;
  for (int i = t; i < n; i += 256) lmax = max(lmax, (unsigned int)(cu[i] >> 32));
#pragma unroll
  for (int o = 32; o > 0; o >>= 1) lmax = max(lmax, __shfl_down(lmax, o));
  if ((t & 63) == 0) atomicMax(&s_kmax, lmax);
  __syncthreads();
  const unsigned int kmax = s_kmax;
  const unsigned long long range = (unsigned long long)(kmax - kmin) + 1ull;

  for (int i = t; i < n; i += 256) {
    unsigned int k = (unsigned int)(cu[i] >> 32);
    unsigned int b = (unsigned int)((((unsigned long long)(k - kmin)) << 10) / range);
    atomicAdd(&hist[b], 1u);
  }
  __syncthreads();
  if (t == 0) {
    unsigned int cum = 0;
    int b = 1023;
    for (; b >= 0; --b) { cum += hist[b]; if (cum >= TOPK) break; }
    s_bstar = (b < 0) ? 0 : b;
  }
  __syncthreads();
  const unsigned int bstar = (unsigned int)s_bstar;

  for (int i = t; i < n; i += 256) {
    unsigned long long key = cu[i];
    unsigned int k = (unsigned int)(key >> 32);
    unsigned int b = (unsigned int)((((unsigned long long)(k - kmin)) << 10) / range);
    if (b >= bstar) {
      unsigned int pos = atomicAdd(&s_gcnt, 1u);
      if (pos < GCAP) keys[pos] = key;
    }
  }
  __syncthreads();
  const int g = min((int)s_gcnt, GCAP);
  for (int i = g + t; i < GCAP; i += 256) keys[i] = 0ull;
  __syncthreads();

  for (int k = 2; k <= GCAP; k <<= 1) {
    for (int j = k >> 1; j > 0; j >>= 1) {
      for (int i = t; i < GCAP; i += 256) {
        int ixj = i ^ j;
        if (ixj > i) {
          unsigned long long a = keys[i], b2 = keys[ixj];
          bool descSeg = ((i & k) == 0);
          bool sw = descSeg ? (a < b2) : (a > b2);
          if (sw) { keys[i] = b2; keys[ixj] = a; }
        }
      }
      __syncthreads();
    }
  }

  if (t < TOPK) {
    unsigned long long key = keys[t];
    unsigned int kk = (unsigned int)(key >> 32);
    unsigned int idx = ~(unsigned int)(key & 0xFFFFFFFFull);
    out[u * TOPK + t] = funsort(kk);
    out[(size_t)B * TOPK + u * TOPK + t] = (float)idx;
  }
}

extern "C" void kernel_launch(void* const* d_in, const int* in_sizes, int n_in,
                              void* d_out, int out_size, void* d_ws, size_t ws_size,
                              hipStream_t stream) {
  const float* user = (const float*)d_in[0];
  const float* corpus = (const float*)d_in[1];
  float* out = (float*)d_out;
  const int B = in_sizes[0] / 64;           // 256
  const int N = in_sizes[1] / 64;           // 1,000,000

  // workspace: cnt[B] u32 @0 | thr[B] f32 @1024 | cand u64 @2048
  unsigned int* cnt = (unsigned int*)d_ws;
  float* thr = (float*)((char*)d_ws + 1024);
  unsigned long long* cand = (unsigned long long*)((char*)d_ws + 2048);

  // CAP=4096: survivors/user ~1120 +/- 280 -> overflow P ~4e-12.
  long long avail = ((long long)ws_size - 2048) / ((long long)B * 8);
  int CAP = 4096;
  if (avail < CAP) CAP = (int)avail;
  if (CAP < 256) CAP = 256;
  const int M = (N < 16384) ? N : 16384;
  const int RANK = 16;

  hipMemsetAsync(cnt, 0, (size_t)B * sizeof(unsigned int), stream);
  k_sample<<<B, 256, 0, stream>>>(user, corpus, thr, M, RANK);
  const int nblk = (int)((N + ROWS_PER_BLOCK - 1) / ROWS_PER_BLOCK);
  k_score<<<nblk, SCORE_TPB, 0, stream>>>(user, corpus, thr, cnt, cand, N, CAP);
  k_select<<<B, 256, 0, stream>>>(cand, cnt, thr, out, B, CAP);
}

// Round 4
// 641.831 us; speedup vs baseline: 1.1009x; 1.1009x over previous
//
#include <hip/hip_runtime.h>
#include <stdint.h>

#define TOPK 100
#define GCAP 2048
#define SCORE_TPB 512
#define TILE_ROWS 128

__device__ __forceinline__ unsigned int fsort(float f) {
  unsigned int u = __float_as_uint(f);
  return (u & 0x80000000u) ? ~u : (u | 0x80000000u);
}
__device__ __forceinline__ float funsort(unsigned int k) {
  unsigned int u = (k & 0x80000000u) ? (k ^ 0x80000000u) : ~k;
  return __uint_as_float(u);
}

// ---------------- Kernel 1: per-user sample threshold (+ cnt zeroing) -------
__global__ void k_sample(const float* __restrict__ user,
                         const float* __restrict__ corpus,
                         float* __restrict__ thr,
                         unsigned int* __restrict__ cnt,
                         int M, int rank) {
  __shared__ float s_scores[16384];
  __shared__ float s_user[64];
  __shared__ unsigned int s_hist[256];
  __shared__ float s_wred[8];
  __shared__ float s_bmax, s_bmin;

  const int u = blockIdx.x;
  const int t = threadIdx.x;
  if (t == 0) cnt[u] = 0u;               // replaces hipMemsetAsync
  if (t < 64) s_user[t] = user[u * 64 + t];
  __syncthreads();

  float uv[64];
#pragma unroll
  for (int i = 0; i < 64; ++i) uv[i] = s_user[i];

  float lmax = -3.0e38f, lmin = 3.0e38f;
  for (int r = t; r < M; r += 256) {
    const float4* row = (const float4*)(corpus + (size_t)r * 64);
    float acc = 0.f;
#pragma unroll
    for (int i = 0; i < 16; ++i) {
      float4 c = row[i];
      acc = fmaf(uv[4*i+0], c.x, acc);
      acc = fmaf(uv[4*i+1], c.y, acc);
      acc = fmaf(uv[4*i+2], c.z, acc);
      acc = fmaf(uv[4*i+3], c.w, acc);
    }
    s_scores[r] = acc;
    lmax = fmaxf(lmax, acc);
    lmin = fminf(lmin, acc);
  }
#pragma unroll
  for (int o = 32; o > 0; o >>= 1) {
    lmax = fmaxf(lmax, __shfl_down(lmax, o));
    lmin = fminf(lmin, __shfl_down(lmin, o));
  }
  if ((t & 63) == 0) { s_wred[t >> 6] = lmax; s_wred[4 + (t >> 6)] = lmin; }
  s_hist[t] = 0u;
  __syncthreads();
  if (t == 0) {
    float bm = s_wred[0], bn = s_wred[4];
    for (int w = 1; w < 4; ++w) { bm = fmaxf(bm, s_wred[w]); bn = fminf(bn, s_wred[4 + w]); }
    s_bmax = bm; s_bmin = bn;
  }
  __syncthreads();
  const float bmax = s_bmax, bmin = s_bmin;
  const float width = (bmax - bmin) / 256.0f;
  const float inv = (width > 0.f) ? 1.0f / width : 0.f;
  for (int r = t; r < M; r += 256) {
    int b = (int)((s_scores[r] - bmin) * inv);
    b = min(max(b, 0), 255);
    atomicAdd(&s_hist[b], 1u);
  }
  __syncthreads();
  if (t == 0) {
    unsigned int cum = 0;
    int b = 255;
    for (; b >= 0; --b) { cum += s_hist[b]; if (cum >= (unsigned int)rank) break; }
    if (b < 0) b = 0;
    thr[u] = bmin + width * (float)b;   // lower edge: conservative
  }
}

// ---------------- Kernel 2: blocked scoring + threshold filter ----------------
// 512 threads; tile = 256 users x 128 rows; thread tile = 8x8.
// User panel as two float4-planes UP[p][dd][ut] -> compute reads are
// lane-contiguous b128 (conflict-free); Cc reads are wave-uniform broadcasts.
__global__ __launch_bounds__(SCORE_TPB) void k_score(
    const float* __restrict__ user,
    const float* __restrict__ corpus,
    const float* __restrict__ thr,
    unsigned int* __restrict__ cnt,
    unsigned long long* __restrict__ cand,
    int N, int CAP) {
  __shared__ __align__(16) float UP[2][32][128];  // 32 KB: plane p, dim dd, 32 ut x float4
  __shared__ __align__(16) float Cc[32][128];     // 16 KB: dim dd, 128 rows

  const int t  = threadIdx.x;
  const int ut = t & 31;        // users ut*8 .. ut*8+7
  const int rt = t >> 5;        // rows  rt*8 .. rt*8+7 (0..15)
  const long long trow0 = (long long)blockIdx.x * TILE_ROWS;

  float thv[8];
#pragma unroll
  for (int i = 0; i < 8; ++i) thv[i] = thr[ut * 8 + i];

  // staging roles
  const int su  = t & 255;      // user this thread stages
  const int sdg = t >> 8;       // 0/1: which 16-dim group of the 32-dim half
  const int sup = (su >> 2) & 1;  // plane
  const int sut = su >> 3;        // ut
  const int ssl = su & 3;         // slot within float4
  const int sr  = t & 127;      // corpus row this thread stages
  const int scg = t >> 7;       // 0..3: which 8-dim group of the half

  float acc[8][8];
#pragma unroll
  for (int i = 0; i < 8; ++i)
#pragma unroll
    for (int j = 0; j < 8; ++j) acc[i][j] = 0.f;

  for (int kh = 0; kh < 2; ++kh) {
    __syncthreads();   // previous compute done before overwriting LDS
    // ---- stage U half: 16 dims of user su -> plane layout ----
    {
      const float* up = user + su * 64 + kh * 32 + sdg * 16;
      float4 a = *(const float4*)(up + 0);
      float4 b = *(const float4*)(up + 4);
      float4 c = *(const float4*)(up + 8);
      float4 d = *(const float4*)(up + 12);
      float tmp[16] = {a.x,a.y,a.z,a.w, b.x,b.y,b.z,b.w,
                       c.x,c.y,c.z,c.w, d.x,d.y,d.z,d.w};
#pragma unroll
      for (int k = 0; k < 16; ++k)
        UP[sup][sdg * 16 + k][sut * 4 + ssl] = tmp[k];
    }
    // ---- stage C half: 8 dims of row trow0+sr ----
    {
      const long long gr = trow0 + sr;
      float tmp[8] = {0.f,0.f,0.f,0.f,0.f,0.f,0.f,0.f};
      if (gr < (long long)N) {
        const float4* cp = (const float4*)(corpus + gr * 64 + kh * 32 + scg * 8);
        float4 a = cp[0], b = cp[1];
        tmp[0]=a.x; tmp[1]=a.y; tmp[2]=a.z; tmp[3]=a.w;
        tmp[4]=b.x; tmp[5]=b.y; tmp[6]=b.z; tmp[7]=b.w;
      }
#pragma unroll
      for (int k = 0; k < 8; ++k) Cc[scg * 8 + k][sr] = tmp[k];
    }
    __syncthreads();
    // ---- compute 32 d-steps: 4 b128 reads -> 64 FMA ----
#pragma unroll 8
    for (int dd = 0; dd < 32; ++dd) {
      float4 ua = ((const float4*)UP[0][dd])[ut];
      float4 ub = ((const float4*)UP[1][dd])[ut];
      float4 ca = ((const float4*)Cc[dd])[rt * 2];
      float4 cb = ((const float4*)Cc[dd])[rt * 2 + 1];
      float us[8] = {ua.x,ua.y,ua.z,ua.w, ub.x,ub.y,ub.z,ub.w};
      float rs[8] = {ca.x,ca.y,ca.z,ca.w, cb.x,cb.y,cb.z,cb.w};
#pragma unroll
      for (int i = 0; i < 8; ++i)
#pragma unroll
        for (int j = 0; j < 8; ++j)
          acc[i][j] = fmaf(us[i], rs[j], acc[i][j]);
    }
  }
  // ---- filter ----
#pragma unroll
  for (int j = 0; j < 8; ++j) {
    const long long grow = trow0 + rt * 8 + j;
    if (grow < (long long)N) {
#pragma unroll
      for (int i = 0; i < 8; ++i) {
        if (acc[i][j] >= thv[i]) {
          const int u = ut * 8 + i;
          unsigned int pos = atomicAdd(&cnt[u], 1u);
          if (pos < (unsigned int)CAP) {
            unsigned long long key = ((unsigned long long)fsort(acc[i][j]) << 32)
                                   | (unsigned long long)(~(unsigned int)grow);
            cand[(size_t)u * (size_t)CAP + pos] = key;
          }
        }
      }
    }
  }
}

// ---------------- Kernel 3: exact top-100 per user ----------------
__global__ void k_select(const unsigned long long* __restrict__ cand,
                         const unsigned int* __restrict__ cnt,
                         const float* __restrict__ thr,
                         float* __restrict__ out,
                         int B, int CAP) {
  __shared__ unsigned long long keys[GCAP];
  __shared__ unsigned int hist[1024];
  __shared__ unsigned int s_kmax, s_gcnt;
  __shared__ int s_bstar;

  const int u = blockIdx.x;
  const int t = threadIdx.x;
  const int n = min((int)cnt[u], CAP);
  const unsigned long long* cu = cand + (size_t)u * (size_t)CAP;
  const unsigned int kmin = fsort(thr[u]);

  if (t == 0) { s_kmax = 0u; s_gcnt = 0u; }
  for (int i = t; i < 1024; i += 256) hist[i] = 0u;
  __syncthreads();

  unsigned int lmax = 0u;
  for (int i = t; i < n; i += 256) lmax = max(lmax, (unsigned int)(cu[i] >> 32));
#pragma unroll
  for (int o = 32; o > 0; o >>= 1) lmax = max(lmax, __shfl_down(lmax, o));
  if ((t & 63) == 0) atomicMax(&s_kmax, lmax);
  __syncthreads();
  const unsigned int kmax = s_kmax;
  const unsigned long long range = (unsigned long long)(kmax - kmin) + 1ull;

  for (int i = t; i < n; i += 256) {
    unsigned int k = (unsigned int)(cu[i] >> 32);
    unsigned int b = (unsigned int)((((unsigned long long)(k - kmin)) << 10) / range);
    atomicAdd(&hist[b], 1u);
  }
  __syncthreads();
  if (t == 0) {
    unsigned int cum = 0;
    int b = 1023;
    for (; b >= 0; --b) { cum += hist[b]; if (cum >= TOPK) break; }
    s_bstar = (b < 0) ? 0 : b;
  }
  __syncthreads();
  const unsigned int bstar = (unsigned int)s_bstar;

  for (int i = t; i < n; i += 256) {
    unsigned long long key = cu[i];
    unsigned int k = (unsigned int)(key >> 32);
    unsigned int b = (unsigned int)((((unsigned long long)(k - kmin)) << 10) / range);
    if (b >= bstar) {
      unsigned int pos = atomicAdd(&s_gcnt, 1u);
      if (pos < GCAP) keys[pos] = key;
    }
  }
  __syncthreads();
  const int g = min((int)s_gcnt, GCAP);
  // dynamic sort size: next pow2 >= g, at least 128
  int S = 128;
  while (S < g) S <<= 1;
  for (int i = g + t; i < S; i += 256) keys[i] = 0ull;
  __syncthreads();

  for (int k = 2; k <= S; k <<= 1) {
    for (int j = k >> 1; j > 0; j >>= 1) {
      for (int i = t; i < S; i += 256) {
        int ixj = i ^ j;
        if (ixj > i) {
          unsigned long long a = keys[i], b2 = keys[ixj];
          bool descSeg = ((i & k) == 0);
          bool sw = descSeg ? (a < b2) : (a > b2);
          if (sw) { keys[i] = b2; keys[ixj] = a; }
        }
      }
      __syncthreads();
    }
  }

  if (t < TOPK) {
    unsigned long long key = keys[t];
    unsigned int kk = (unsigned int)(key >> 32);
    unsigned int idx = ~(unsigned int)(key & 0xFFFFFFFFull);
    out[u * TOPK + t] = funsort(kk);
    out[(size_t)B * TOPK + u * TOPK + t] = (float)idx;
  }
}

extern "C" void kernel_launch(void* const* d_in, const int* in_sizes, int n_in,
                              void* d_out, int out_size, void* d_ws, size_t ws_size,
                              hipStream_t stream) {
  const float* user = (const float*)d_in[0];
  const float* corpus = (const float*)d_in[1];
  float* out = (float*)d_out;
  const int B = in_sizes[0] / 64;           // 256
  const int N = in_sizes[1] / 64;           // 1,000,000

  // workspace: cnt[B] u32 @0 | thr[B] f32 @1024 | cand u64 @2048
  unsigned int* cnt = (unsigned int*)d_ws;
  float* thr = (float*)((char*)d_ws + 1024);
  unsigned long long* cand = (unsigned long long*)((char*)d_ws + 2048);

  // CAP=4096: survivors/user ~1120 +/- 280 -> overflow P ~4e-12.
  long long avail = ((long long)ws_size - 2048) / ((long long)B * 8);
  int CAP = 4096;
  if (avail < CAP) CAP = (int)avail;
  if (CAP < 256) CAP = 256;
  const int M = (N < 16384) ? N : 16384;
  const int RANK = 16;

  k_sample<<<B, 256, 0, stream>>>(user, corpus, thr, cnt, M, RANK);
  const int nblk = (int)((N + TILE_ROWS - 1) / TILE_ROWS);
  k_score<<<nblk, SCORE_TPB, 0, stream>>>(user, corpus, thr, cnt, cand, N, CAP);
  k_select<<<B, 256, 0, stream>>>(cand, cnt, thr, out, B, CAP);
}

// Round 5
// 607.756 us; speedup vs baseline: 1.1626x; 1.0561x over previous
//
#include <hip/hip_runtime.h>
#include <stdint.h>

#define TOPK 100
#define GCAP 2048
#define FIL_GRID 4096

typedef __attribute__((ext_vector_type(8))) short bf16x8;
typedef __attribute__((ext_vector_type(4))) float f32x4;

__device__ __forceinline__ unsigned int fsort(float f) {
  unsigned int u = __float_as_uint(f);
  return (u & 0x80000000u) ? ~u : (u | 0x80000000u);
}
__device__ __forceinline__ float funsort(unsigned int k) {
  unsigned int u = (k & 0x80000000u) ? (k ^ 0x80000000u) : ~k;
  return __uint_as_float(u);
}
__device__ __forceinline__ unsigned short f2bf(float f) {
  unsigned int u = __float_as_uint(f);
  unsigned int r = (u + 0x7fffu + ((u >> 16) & 1u)) >> 16;  // RNE
  return (unsigned short)r;
}

// ------- Kernel 1: per-user sample threshold + cnt zero + user bf16 panel ----
__global__ void k_sample(const float* __restrict__ user,
                         const float* __restrict__ corpus,
                         float* __restrict__ thr,
                         unsigned int* __restrict__ cnt,
                         unsigned short* __restrict__ ubf,
                         int M, int rank) {
  __shared__ float s_scores[16384];
  __shared__ float s_user[64];
  __shared__ unsigned int s_hist[256];
  __shared__ float s_wred[8];
  __shared__ float s_bmax, s_bmin;

  const int u = blockIdx.x;
  const int t = threadIdx.x;
  if (t == 0) cnt[u] = 0u;
  if (t < 64) {
    float v = user[u * 64 + t];
    s_user[t] = v;
    ubf[u * 64 + t] = f2bf(v);      // bf16 user panel for k_filter
  }
  __syncthreads();

  float uv[64];
#pragma unroll
  for (int i = 0; i < 64; ++i) uv[i] = s_user[i];

  float lmax = -3.0e38f, lmin = 3.0e38f;
  for (int r = t; r < M; r += 256) {
    const float4* row = (const float4*)(corpus + (size_t)r * 64);
    float acc = 0.f;
#pragma unroll
    for (int i = 0; i < 16; ++i) {
      float4 c = row[i];
      acc = fmaf(uv[4*i+0], c.x, acc);
      acc = fmaf(uv[4*i+1], c.y, acc);
      acc = fmaf(uv[4*i+2], c.z, acc);
      acc = fmaf(uv[4*i+3], c.w, acc);
    }
    s_scores[r] = acc;
    lmax = fmaxf(lmax, acc);
    lmin = fminf(lmin, acc);
  }
#pragma unroll
  for (int o = 32; o > 0; o >>= 1) {
    lmax = fmaxf(lmax, __shfl_down(lmax, o));
    lmin = fminf(lmin, __shfl_down(lmin, o));
  }
  if ((t & 63) == 0) { s_wred[t >> 6] = lmax; s_wred[4 + (t >> 6)] = lmin; }
  s_hist[t] = 0u;
  __syncthreads();
  if (t == 0) {
    float bm = s_wred[0], bn = s_wred[4];
    for (int w = 1; w < 4; ++w) { bm = fmaxf(bm, s_wred[w]); bn = fminf(bn, s_wred[4 + w]); }
    s_bmax = bm; s_bmin = bn;
  }
  __syncthreads();
  const float bmax = s_bmax, bmin = s_bmin;
  const float width = (bmax - bmin) / 256.0f;
  const float inv = (width > 0.f) ? 1.0f / width : 0.f;
  for (int r = t; r < M; r += 256) {
    int b = (int)((s_scores[r] - bmin) * inv);
    b = min(max(b, 0), 255);
    atomicAdd(&s_hist[b], 1u);
  }
  __syncthreads();
  if (t == 0) {
    unsigned int cum = 0;
    int b = 255;
    for (; b >= 0; --b) { cum += s_hist[b]; if (cum >= (unsigned int)rank) break; }
    if (b < 0) b = 0;
    thr[u] = bmin + width * (float)b;   // lower edge: conservative
  }
}

// ------- Kernel 2: MFMA bf16 filter --------------------------------------
// 256 thr = 4 waves. Wave w owns users w*64..w*64+63 (4 tiles of 16).
// Per 16-row tile: A-frag = corpus rows (fp32->bf16 in-flight), 8 MFMAs.
// D mapping (m89-verified): n(user)=lane&15, m(row)=(lane>>4)*4+reg.
__global__ __launch_bounds__(256) void k_filter(
    const float* __restrict__ corpus,
    const unsigned short* __restrict__ ubf,
    const float* __restrict__ thr,
    unsigned int* __restrict__ cnt,
    unsigned long long* __restrict__ cand,
    int N, int CAP, int ntiles, float margin) {
  const int t = threadIdx.x;
  const int lane = t & 63;
  const int wave = t >> 6;            // 0..3
  const int l15 = lane & 15;
  const int l4  = lane >> 4;          // 0..3
  const int ubase = wave * 64;

  // B-fragments: user uu = ubase + ut*16 + l15, dims kh*32 + l4*8 .. +7
  bf16x8 bf[4][2];
#pragma unroll
  for (int ut = 0; ut < 4; ++ut) {
    const int uu = ubase + ut * 16 + l15;
#pragma unroll
    for (int kh = 0; kh < 2; ++kh)
      bf[ut][kh] = *(const bf16x8*)(ubf + uu * 64 + kh * 32 + l4 * 8);
  }
  float thv[4];
#pragma unroll
  for (int ut = 0; ut < 4; ++ut) thv[ut] = thr[ubase + ut * 16 + l15] - margin;

  for (int tile = blockIdx.x; tile < ntiles; tile += gridDim.x) {
    const int rb = tile << 4;
    const long long rowc = (long long)min(rb + l15, N - 1);
    const float4* rp = (const float4*)(corpus + rowc * 64);
    // A-frags: lane holds row (l15), dims kh*32 + l4*8 .. +7
    float4 a00 = rp[l4 * 2 + 0];
    float4 a01 = rp[l4 * 2 + 1];
    float4 a10 = rp[8 + l4 * 2 + 0];
    float4 a11 = rp[8 + l4 * 2 + 1];
    bf16x8 af0, af1;
    af0[0] = (short)f2bf(a00.x); af0[1] = (short)f2bf(a00.y);
    af0[2] = (short)f2bf(a00.z); af0[3] = (short)f2bf(a00.w);
    af0[4] = (short)f2bf(a01.x); af0[5] = (short)f2bf(a01.y);
    af0[6] = (short)f2bf(a01.z); af0[7] = (short)f2bf(a01.w);
    af1[0] = (short)f2bf(a10.x); af1[1] = (short)f2bf(a10.y);
    af1[2] = (short)f2bf(a10.z); af1[3] = (short)f2bf(a10.w);
    af1[4] = (short)f2bf(a11.x); af1[5] = (short)f2bf(a11.y);
    af1[6] = (short)f2bf(a11.z); af1[7] = (short)f2bf(a11.w);

    f32x4 acc[4];
#pragma unroll
    for (int ut = 0; ut < 4; ++ut) acc[ut] = (f32x4){0.f, 0.f, 0.f, 0.f};
#pragma unroll
    for (int ut = 0; ut < 4; ++ut) {
      acc[ut] = __builtin_amdgcn_mfma_f32_16x16x32_bf16(af0, bf[ut][0], acc[ut], 0, 0, 0);
      acc[ut] = __builtin_amdgcn_mfma_f32_16x16x32_bf16(af1, bf[ut][1], acc[ut], 0, 0, 0);
    }
#pragma unroll
    for (int ut = 0; ut < 4; ++ut) {
      const int uu = ubase + ut * 16 + l15;
#pragma unroll
      for (int r = 0; r < 4; ++r) {
        const int row = rb + l4 * 4 + r;
        const float s = acc[ut][r];
        if (s >= thv[ut] && row < N) {
          unsigned int pos = atomicAdd(&cnt[uu], 1u);
          if (pos < (unsigned int)CAP)
            cand[(size_t)uu * (size_t)CAP + pos] = (unsigned long long)(unsigned int)row;
        }
      }
    }
  }
}

// ------- Kernel 3: exact fp32 rescore of survivors (in-place keys) --------
__global__ void k_rescore(const float* __restrict__ user,
                          const float* __restrict__ corpus,
                          const unsigned int* __restrict__ cnt,
                          unsigned long long* __restrict__ cand,
                          int CAP) {
  __shared__ float su[64];
  const int u = blockIdx.x;
  const int t = threadIdx.x;
  if (t < 64) su[t] = user[u * 64 + t];
  __syncthreads();
  float uv[64];
#pragma unroll
  for (int i = 0; i < 64; ++i) uv[i] = su[i];
  const int n = min((int)cnt[u], CAP);
  for (int i = t; i < n; i += 256) {
    const unsigned int row = (unsigned int)cand[(size_t)u * (size_t)CAP + i];
    const float4* rp = (const float4*)(corpus + (size_t)row * 64);
    float acc = 0.f;
#pragma unroll
    for (int k = 0; k < 16; ++k) {
      float4 c = rp[k];
      acc = fmaf(uv[4*k+0], c.x, acc);
      acc = fmaf(uv[4*k+1], c.y, acc);
      acc = fmaf(uv[4*k+2], c.z, acc);
      acc = fmaf(uv[4*k+3], c.w, acc);
    }
    cand[(size_t)u * (size_t)CAP + i] = ((unsigned long long)fsort(acc) << 32)
                                      | (unsigned long long)(~row);
  }
}

// ------- Kernel 4: exact top-100 per user ---------------------------------
__global__ void k_select(const unsigned long long* __restrict__ cand,
                         const unsigned int* __restrict__ cnt,
                         float* __restrict__ out,
                         int B, int CAP) {
  __shared__ unsigned long long keys[GCAP];
  __shared__ unsigned int hist[1024];
  __shared__ unsigned int s_kmax, s_kmin, s_gcnt;
  __shared__ int s_bstar;

  const int u = blockIdx.x;
  const int t = threadIdx.x;
  const int n = min((int)cnt[u], CAP);
  const unsigned long long* cu = cand + (size_t)u * (size_t)CAP;

  if (t == 0) { s_kmax = 0u; s_kmin = 0xFFFFFFFFu; s_gcnt = 0u; }
  for (int i = t; i < 1024; i += 256) hist[i] = 0u;
  __syncthreads();

  unsigned int lmax = 0u, lmin = 0xFFFFFFFFu;
  for (int i = t; i < n; i += 256) {
    unsigned int k = (unsigned int)(cu[i] >> 32);
    lmax = max(lmax, k); lmin = min(lmin, k);
  }
#pragma unroll
  for (int o = 32; o > 0; o >>= 1) {
    lmax = max(lmax, __shfl_down(lmax, o));
    lmin = min(lmin, __shfl_down(lmin, o));
  }
  if ((t & 63) == 0) { atomicMax(&s_kmax, lmax); atomicMin(&s_kmin, lmin); }
  __syncthreads();
  const unsigned int kmax = s_kmax, kmin = s_kmin;
  const unsigned long long range = (unsigned long long)(kmax - kmin) + 1ull;

  for (int i = t; i < n; i += 256) {
    unsigned int k = (unsigned int)(cu[i] >> 32);
    unsigned int b = (unsigned int)((((unsigned long long)(k - kmin)) << 10) / range);
    atomicAdd(&hist[min(b, 1023u)], 1u);
  }
  __syncthreads();
  if (t == 0) {
    unsigned int cum = 0;
    int b = 1023;
    for (; b >= 0; --b) { cum += hist[b]; if (cum >= TOPK) break; }
    s_bstar = (b < 0) ? 0 : b;
  }
  __syncthreads();
  const unsigned int bstar = (unsigned int)s_bstar;

  for (int i = t; i < n; i += 256) {
    unsigned long long key = cu[i];
    unsigned int k = (unsigned int)(key >> 32);
    unsigned int b = min((unsigned int)((((unsigned long long)(k - kmin)) << 10) / range), 1023u);
    if (b >= bstar) {
      unsigned int pos = atomicAdd(&s_gcnt, 1u);
      if (pos < GCAP) keys[pos] = key;
    }
  }
  __syncthreads();
  const int g = min((int)s_gcnt, GCAP);
  int S = 128;
  while (S < g) S <<= 1;
  for (int i = g + t; i < S; i += 256) keys[i] = 0ull;
  __syncthreads();

  for (int k = 2; k <= S; k <<= 1) {
    for (int j = k >> 1; j > 0; j >>= 1) {
      for (int i = t; i < S; i += 256) {
        int ixj = i ^ j;
        if (ixj > i) {
          unsigned long long a = keys[i], b2 = keys[ixj];
          bool descSeg = ((i & k) == 0);
          bool sw = descSeg ? (a < b2) : (a > b2);
          if (sw) { keys[i] = b2; keys[ixj] = a; }
        }
      }
      __syncthreads();
    }
  }

  if (t < TOPK) {
    unsigned long long key = keys[t];
    unsigned int kk = (unsigned int)(key >> 32);
    unsigned int idx = ~(unsigned int)(key & 0xFFFFFFFFull);
    out[u * TOPK + t] = funsort(kk);
    out[(size_t)B * TOPK + u * TOPK + t] = (float)idx;
  }
}

extern "C" void kernel_launch(void* const* d_in, const int* in_sizes, int n_in,
                              void* d_out, int out_size, void* d_ws, size_t ws_size,
                              hipStream_t stream) {
  const float* user = (const float*)d_in[0];
  const float* corpus = (const float*)d_in[1];
  float* out = (float*)d_out;
  const int B = in_sizes[0] / 64;           // 256
  const int N = in_sizes[1] / 64;           // 1,000,000

  // ws: cnt[B] u32 @0 | thr[B] f32 @1024 | ubf[B*64] u16 @2048 | cand u64 @34816
  unsigned int* cnt = (unsigned int*)d_ws;
  float* thr = (float*)((char*)d_ws + 1024);
  unsigned short* ubf = (unsigned short*)((char*)d_ws + 2048);
  unsigned long long* cand = (unsigned long long*)((char*)d_ws + 34816);

  long long avail = ((long long)ws_size - 34816) / ((long long)B * 8);
  int CAP = 4096;                    // survivors ~1165 +/- 280
  if (avail < CAP) CAP = (int)avail;
  if (CAP < 256) CAP = 256;
  const int M = (N < 16384) ? N : 16384;
  const int RANK = 16;
  const float MARGIN = 0.25f;        // ~8 sigma of bf16 score error
  const int ntiles = (N + 15) >> 4;

  k_sample<<<B, 256, 0, stream>>>(user, corpus, thr, cnt, ubf, M, RANK);
  k_filter<<<FIL_GRID, 256, 0, stream>>>(corpus, ubf, thr, cnt, cand, N, CAP, ntiles, MARGIN);
  k_rescore<<<B, 256, 0, stream>>>(user, corpus, cnt, cand, CAP);
  k_select<<<B, 256, 0, stream>>>(cand, cnt, out, B, CAP);
}